// Round 7
// baseline (274.195 us; speedup 1.0000x reference)
//
#include <hip/hip_runtime.h>

// ---------------------------------------------------------------------------
// RoPE GQA attention block, MI355X bf16-MFMA implementation (round 7).
// B=2 S=2048 D=2048 H=16 HKV=4 DH=128.  head h uses kv head h%4 (torch tile).
// Round 7: flash_attn LDS-roofline fix — 64 q-rows/wave (4 q-groups) so each
// K/V LDS fragment read feeds 4 MFMAs (was 2). 512-VGPR budget via
// __launch_bounds__(256,1); grid = 1 block/CU. Dbuf pipeline retained.
// ---------------------------------------------------------------------------

typedef __attribute__((ext_vector_type(8))) short  short8;
typedef __attribute__((ext_vector_type(8))) __bf16 bf16x8;
typedef __attribute__((ext_vector_type(4))) float  f32x4;

#define B_   2
#define S_   2048
#define D_   2048
#define H_   16
#define HKV_ 4
#define DH_  128
#define M_   4096  // B*S
#define NQKV 3072  // fused projection width: 2048 Q + 512 K + 512 V

static __device__ __forceinline__ ushort f2bf(float f) {
  __bf16 h = (__bf16)f;                      // native cvt (RNE)
  return __builtin_bit_cast(unsigned short, h);
}
static __device__ __forceinline__ float bf2f(ushort u) {
  union { unsigned u; float f; } v; v.u = ((unsigned)u) << 16;
  return v.f;
}
static __device__ __forceinline__ f32x4 mfma16(short8 a, short8 b, f32x4 c) {
  return __builtin_amdgcn_mfma_f32_16x16x32_bf16(
      __builtin_bit_cast(bf16x8, a), __builtin_bit_cast(bf16x8, b), c, 0, 0, 0);
}
// async global->LDS, 16B per lane; lds base must be wave-uniform.
static __device__ __forceinline__ void gload16(const ushort* g, ushort* l) {
  __builtin_amdgcn_global_load_lds(
      (const __attribute__((address_space(1))) unsigned int*)g,
      (__attribute__((address_space(3))) unsigned int*)l, 16, 0, 0);
}

// ---------------- elementwise f32 -> bf16 ----------------------------------
__global__ void conv_f32_bf16(const float* __restrict__ in,
                              ushort* __restrict__ out, int n4) {
  int i = blockIdx.x * blockDim.x + threadIdx.x;
  if (i >= n4) return;
  float4 v = ((const float4*)in)[i];
  ushort4 o;
  o.x = f2bf(v.x); o.y = f2bf(v.y); o.z = f2bf(v.z); o.w = f2bf(v.w);
  ((ushort4*)out)[i] = o;
}

// ---------------- transpose + convert: W[R][C] f32 -> Wt[C][R] bf16 --------
__global__ void transpose_conv(const float* __restrict__ in,
                               ushort* __restrict__ out, int R, int C) {
  __shared__ float tile[32][33];
  int c0 = blockIdx.x * 32, r0 = blockIdx.y * 32;
  int tx = threadIdx.x, ty = threadIdx.y;  // (32,8)
#pragma unroll
  for (int i = 0; i < 32; i += 8)
    tile[ty + i][tx] = in[(size_t)(r0 + ty + i) * C + c0 + tx];
  __syncthreads();
#pragma unroll
  for (int i = 0; i < 32; i += 8)
    out[(size_t)(c0 + ty + i) * R + r0 + tx] = f2bf(tile[tx][ty + i]);
}

// ---------------- bf16 transpose for V: QKV[.,2560+kv*128+d] -> [B,kv,128,S]
__global__ void transpose_v(const ushort* __restrict__ in,
                            ushort* __restrict__ out, int src_stride) {
  __shared__ ushort tile[32][33];
  int bkv = blockIdx.z;                       // b*4+kv
  const ushort* src = in + (size_t)(bkv >> 2) * S_ * src_stride + (bkv & 3) * DH_;
  ushort* dst = out + (size_t)bkv * DH_ * S_;
  int d0 = blockIdx.x * 32, s0 = blockIdx.y * 32;
  int tx = threadIdx.x, ty = threadIdx.y;
#pragma unroll
  for (int i = 0; i < 32; i += 8)
    tile[ty + i][tx] = src[(size_t)(s0 + ty + i) * src_stride + d0 + tx];
  __syncthreads();
#pragma unroll
  for (int i = 0; i < 32; i += 8)
    dst[(size_t)(d0 + ty + i) * S_ + s0 + tx] = tile[tx][ty + i];
}

// ---------------- RoPE cos/sin table [S][64] -------------------------------
__global__ void rope_table_k(float2* __restrict__ tab) {
  int i = blockIdx.x * blockDim.x + threadIdx.x;  // < S_*64
  int pos = i >> 6, f = i & 63;
  float freq = powf(10000.0f, -(float)f / 64.0f);
  float a = (float)pos * freq;
  tab[i] = make_float2(cosf(a), sinf(a));
}

// ---------------- RoPE in-place on bf16, strided rows ----------------------
__global__ void rope_apply_k(ushort* __restrict__ t,
                             const float2* __restrict__ tab,
                             int total, int ppr_shift, int row_stride,
                             float oscale) {
  int idx = blockIdx.x * blockDim.x + threadIdx.x;
  if (idx >= total) return;
  int row = idx >> ppr_shift;
  int p   = idx & ((1 << ppr_shift) - 1);
  int head = p >> 6, fi = p & 63;
  int pos = row & (S_ - 1);
  float2 cs = tab[(pos << 6) + fi];
  size_t off = (size_t)row * row_stride + head * DH_ + 2 * fi;
  ushort2 v = *(ushort2*)&t[off];
  float x0 = bf2f(v.x), x1 = bf2f(v.y);
  ushort2 o;
  o.x = f2bf((x0 * cs.x - x1 * cs.y) * oscale);
  o.y = f2bf((x0 * cs.y + x1 * cs.x) * oscale);
  *(ushort2*)&t[off] = o;
}

// ---------------- bf16 GEMM: C[M,N] = A[M,K] * Bt[N,K]^T -------------------
// m97 structure: 128x128 tile, BK=32, 4 waves (2x2), global_load_lds w16.
template <typename OutT>
__global__ __launch_bounds__(256) void gemm_bt(const ushort* __restrict__ A,
                                               const ushort* __restrict__ Bt,
                                               OutT* __restrict__ C,
                                               int M, int N, int K) {
  __shared__ ushort As[128 * 32];
  __shared__ ushort Bs[128 * 32];
  const int tid = threadIdx.x;
  const int lane = tid & 63, wave = tid >> 6;
  const int wm = (wave >> 1) * 64, wn = (wave & 1) * 64;
  const int bm = blockIdx.x * 128, bn = blockIdx.y * 128;
  const int l16 = lane & 15, l4 = lane >> 4;

  // staging: thread -> row tid>>2 (=wave*16+lane>>2), cols (tid&3)*8..+7
  const ushort* gA = A  + (size_t)(bm + (tid >> 2)) * K + (tid & 3) * 8;
  const ushort* gB = Bt + (size_t)(bn + (tid >> 2)) * K + (tid & 3) * 8;
  ushort* lA0 = &As[wave * 512];          // rows 0..63 (lane*16B linear)
  ushort* lA1 = &As[2048 + wave * 512];   // rows 64..127
  ushort* lB0 = &Bs[wave * 512];
  ushort* lB1 = &Bs[2048 + wave * 512];
  const size_t rstep = (size_t)64 * K;

  f32x4 acc[4][4] = {};

  for (int k0 = 0; k0 < K; k0 += 32) {
    __syncthreads();                       // readers of prev tile done
    gload16(gA + k0,         lA0);
    gload16(gA + k0 + rstep, lA1);
    gload16(gB + k0,         lB0);
    gload16(gB + k0 + rstep, lB1);
    __syncthreads();                       // vmcnt(0) drained -> tile visible
    short8 af[4], bfr[4];
#pragma unroll
    for (int m = 0; m < 4; ++m)
      af[m] = *(const short8*)&As[(wm + m * 16 + l16) * 32 + l4 * 8];
#pragma unroll
    for (int n = 0; n < 4; ++n)
      bfr[n] = *(const short8*)&Bs[(wn + n * 16 + l16) * 32 + l4 * 8];
#pragma unroll
    for (int m = 0; m < 4; ++m)
#pragma unroll
      for (int n = 0; n < 4; ++n)
        acc[m][n] = mfma16(af[m], bfr[n], acc[m][n]);
  }

  // epilogue: C/D layout col=lane&15, row=(lane>>4)*4+reg
#pragma unroll
  for (int m = 0; m < 4; ++m) {
#pragma unroll
    for (int n = 0; n < 4; ++n) {
#pragma unroll
      for (int r = 0; r < 4; ++r) {
        size_t row = bm + wm + m * 16 + l4 * 4 + r;
        size_t col = bn + wn + n * 16 + l16;
        if constexpr (sizeof(OutT) == 2)
          C[row * N + col] = f2bf(acc[m][n][r]);
        else
          C[row * N + col] = acc[m][n][r];
      }
    }
  }
}

// ---------------- flash attention (round 7) --------------------------------
// grid (S/256, B*H); 4 waves/block, wave owns 64 q rows (4 q-groups of 16);
// KBLK=64, double-buffered LDS. Each K/V fragment read feeds 4 MFMAs.
// Swapped QK^T with interleaved key mapping keeps P entirely in registers:
//   s[qg][c][r] (lane l16,l4) = S[q=qg*16+l16][key = 32*(c>>1)+8*l4+4*(c&1)+r]
//   => pa[qg][ks][j] = P[q][ks*32 + l4*8 + j] = cvt(s[qg][2ks+(j>>2)][j&3]).
__global__ __launch_bounds__(256, 1) void flash_attn(const ushort* __restrict__ Qp,
                                                     const ushort* __restrict__ Kp,
                                                     const ushort* __restrict__ Vt,
                                                     ushort* __restrict__ Oa) {
  __shared__ ushort Ks[2][64 * 128];    // [key][d], swizzle (r&3)|((r>>3)&1)<<2
  __shared__ ushort Vs[2][128 * 64];    // [d][key], swizzle d&7
  const int tid = threadIdx.x;
  const int lane = tid & 63, wave = tid >> 6;
  const int l16 = lane & 15, l4 = lane >> 4;
  const int bh = blockIdx.y;
  const int b = bh >> 4, h = bh & 15, kv = h & 3;
  const int q0 = blockIdx.x * 256 + wave * 64;

  // Q fragments: 4 q-groups, lane holds Q[q0+qg*16+l16][d-slice]
  short8 qf[4][4];
#pragma unroll
  for (int qg = 0; qg < 4; ++qg) {
    const ushort* qrow =
        Qp + ((size_t)(b * S_ + q0 + qg * 16 + l16)) * NQKV + h * DH_ + l4 * 8;
#pragma unroll
    for (int kk = 0; kk < 4; ++kk) qf[qg][kk] = *(const short8*)(qrow + kk * 32);
  }

  const ushort* kbase = Kp + (size_t)(b * S_) * NQKV + kv * DH_;
  const ushort* vbase = Vt + (size_t)(b * HKV_ + kv) * DH_ * S_;

  float mreg[4] = {-1e30f, -1e30f, -1e30f, -1e30f};
  float lsum[4] = {0.f, 0.f, 0.f, 0.f};
  f32x4 o[4][8] = {};

  // read-side swizzles (constant per lane)
  const int kswz = (l16 & 3) | (((l16 >> 2) & 1) << 2);  // = swzK(krow) below
  const int vswz = l16 & 7;

  // staging thread mapping (constant per thread)
  const int krT = wave * 16 + (lane >> 4);               // + i*4
  const int kcT = lane & 15;
  const int vrT = wave * 32 + (lane >> 3);               // + i*8
  const int vcT = lane & 7;

  auto stage = [&](int t, int buf) {
#pragma unroll
    for (int i = 0; i < 4; ++i) {
      int r = krT + i * 4;                               // K tile row
      int swz = (r & 3) | (((r >> 3) & 1) << 2);
      gload16(kbase + (size_t)(t * 64 + r) * NQKV + ((kcT ^ swz) * 8),
              &Ks[buf][(wave * 16 + i * 4) * 128]);
      int d = vrT + i * 8;                               // V tile row (d)
      gload16(vbase + (size_t)d * S_ + t * 64 + ((vcT ^ (d & 7)) * 8),
              &Vs[buf][(wave * 32 + i * 8) * 64]);
    }
  };

  const int NT = S_ / 64;
  stage(0, 0);
  __syncthreads();                        // vmcnt(0) drain: buf0 ready

  for (int t = 0; t < NT; ++t) {
    const int cur = t & 1;
    if (t + 1 < NT) stage(t + 1, cur ^ 1);  // issue next tile; waits at the
                                            // end-of-iter barrier (T3)

    // ---- QK^T (swapped, interleaved keys), K-fragments shared by 4 qg ----
    f32x4 s[4][4] = {};
    __builtin_amdgcn_s_setprio(1);
#pragma unroll
    for (int c = 0; c < 4; ++c) {
      const int krow = 32 * (c >> 1) + 8 * (l16 >> 2) + 4 * (c & 1) + (l16 & 3);
#pragma unroll
      for (int kk = 0; kk < 4; ++kk) {
        short8 kf = *(const short8*)&Ks[cur][krow * 128 + (((kk * 4 + l4) ^ kswz) * 8)];
        s[0][c] = mfma16(kf, qf[0][kk], s[0][c]);
        s[1][c] = mfma16(kf, qf[1][kk], s[1][c]);
        s[2][c] = mfma16(kf, qf[2][kk], s[2][c]);
        s[3][c] = mfma16(kf, qf[3][kk], s[3][c]);
      }
    }
    __builtin_amdgcn_s_setprio(0);

    // ---- online softmax, per lane q = qg*16 + l16 (exp2 domain) ----
    float tmax[4];
#pragma unroll
    for (int qg = 0; qg < 4; ++qg) {
      float a = fmaxf(fmaxf(s[qg][0][0], s[qg][0][1]), fmaxf(s[qg][0][2], s[qg][0][3]));
#pragma unroll
      for (int c = 1; c < 4; ++c) {
        a = fmaxf(a, fmaxf(fmaxf(s[qg][c][0], s[qg][c][1]),
                           fmaxf(s[qg][c][2], s[qg][c][3])));
      }
      a = fmaxf(a, __shfl_xor(a, 16));
      tmax[qg] = fmaxf(a, __shfl_xor(a, 32));
    }

    bool ok = (tmax[0] - mreg[0] <= 8.0f) && (tmax[1] - mreg[1] <= 8.0f) &&
              (tmax[2] - mreg[2] <= 8.0f) && (tmax[3] - mreg[3] <= 8.0f);
    if (!__all(ok)) {                     // defer-max (T13): rare rescale
#pragma unroll
      for (int qg = 0; qg < 4; ++qg) {
        float mn = fmaxf(mreg[qg], tmax[qg]);
        float alpha = __builtin_amdgcn_exp2f(mreg[qg] - mn);
        mreg[qg] = mn;
        lsum[qg] *= alpha;
        float af[4];
#pragma unroll
        for (int r = 0; r < 4; ++r)
          af[r] = __shfl(alpha, (lane & 48) + l4 * 4 + r);
#pragma unroll
        for (int g = 0; g < 8; ++g)
#pragma unroll
          for (int r = 0; r < 4; ++r) o[qg][g][r] *= af[r];
      }
    }

    // ---- P in registers: pa[qg][ks][j] = P[q][ks*32 + l4*8 + j] ----
    short8 pa[4][2];
#pragma unroll
    for (int qg = 0; qg < 4; ++qg) {
      float rs = 0.f;
#pragma unroll
      for (int ks = 0; ks < 2; ++ks) {
        short8 pk;
#pragma unroll
        for (int j = 0; j < 8; ++j) {
          float p = __builtin_amdgcn_exp2f(s[qg][2 * ks + (j >> 2)][j & 3] - mreg[qg]);
          rs += p;
          pk[j] = (short)f2bf(p);
        }
        pa[qg][ks] = pk;
      }
      float r2 = rs + __shfl_xor(rs, 16);
      lsum[qg] += r2 + __shfl_xor(r2, 32);
    }

    // ---- PV: V-fragments shared by all 4 q-groups ----
    __builtin_amdgcn_s_setprio(1);
#pragma unroll
    for (int ks = 0; ks < 2; ++ks) {
#pragma unroll
      for (int g = 0; g < 8; ++g) {
        const int d = g * 16 + l16;
        short8 vf = *(const short8*)&Vs[cur][d * 64 + (((ks * 4 + l4) ^ vswz) * 8)];
        o[0][g] = mfma16(pa[0][ks], vf, o[0][g]);
        o[1][g] = mfma16(pa[1][ks], vf, o[1][g]);
        o[2][g] = mfma16(pa[2][ks], vf, o[2][g]);
        o[3][g] = mfma16(pa[3][ks], vf, o[3][g]);
      }
    }
    __builtin_amdgcn_s_setprio(0);

    __syncthreads();                      // drains t+1 loads (hidden under the
                                          // compute above) + publishes buffer
  }

  // epilogue: O rows are q = qg*16 + l4*4 + r; fetch 1/l from lane l16 == qrow
#pragma unroll
  for (int qg = 0; qg < 4; ++qg) {
    float inv = 1.0f / lsum[qg];
    float invq[4];
#pragma unroll
    for (int r = 0; r < 4; ++r)
      invq[r] = __shfl(inv, (lane & 48) + l4 * 4 + r);
    ushort* op = Oa + (size_t)(b * S_ + q0 + qg * 16) * D_ + h * DH_;
#pragma unroll
    for (int g = 0; g < 8; ++g)
#pragma unroll
      for (int r = 0; r < 4; ++r)
        op[(size_t)(l4 * 4 + r) * D_ + g * 16 + l16] = f2bf(o[qg][g][r] * invq[r]);
  }
}

// ---------------------------------------------------------------------------
extern "C" void kernel_launch(void* const* d_in, const int* in_sizes, int n_in,
                              void* d_out, int out_size, void* d_ws, size_t ws_size,
                              hipStream_t stream) {
  (void)in_sizes; (void)n_in; (void)out_size; (void)ws_size;
  const float* x  = (const float*)d_in[0];
  const float* Wq = (const float*)d_in[1];
  const float* Wk = (const float*)d_in[2];
  const float* Wv = (const float*)d_in[3];
  const float* Wo = (const float*)d_in[4];
  float* out = (float*)d_out;

  size_t off = 0;
  auto carve = [&](size_t bytes) -> void* {
    void* p = (char*)d_ws + off;
    off += (bytes + 255) & ~(size_t)255;
    return p;
  };
  ushort* xb    = (ushort*)carve((size_t)M_ * D_ * 2);
  ushort* Wqkvt = (ushort*)carve((size_t)NQKV * D_ * 2);   // [3072][2048]
  ushort* Wot   = (ushort*)carve((size_t)D_ * D_ * 2);
  ushort* QKV   = (ushort*)carve((size_t)M_ * NQKV * 2);   // [4096][3072]
  ushort* Vt    = (ushort*)carve((size_t)M_ * 512 * 2);
  ushort* attn  = (ushort*)carve((size_t)M_ * D_ * 2);
  float2* tab   = (float2*)carve((size_t)S_ * 64 * sizeof(float2));

  // 1. casts / transposes of inputs (K,V weight rows appended after Q's)
  conv_f32_bf16<<<(M_ * D_ / 4 + 255) / 256, 256, 0, stream>>>(x, xb, M_ * D_ / 4);
  transpose_conv<<<dim3(64, 64), dim3(32, 8), 0, stream>>>(Wq, Wqkvt, 2048, 2048);
  transpose_conv<<<dim3(16, 64), dim3(32, 8), 0, stream>>>(Wk, Wqkvt + (size_t)2048 * 2048, 2048, 512);
  transpose_conv<<<dim3(16, 64), dim3(32, 8), 0, stream>>>(Wv, Wqkvt + (size_t)2560 * 2048, 2048, 512);
  transpose_conv<<<dim3(64, 64), dim3(32, 8), 0, stream>>>(Wo, Wot, 2048, 2048);
  rope_table_k<<<(S_ * 64) / 256, 256, 0, stream>>>(tab);

  // 2. fused QKV projection: [4096,2048] x [3072,2048]^T -> [4096,3072]
  gemm_bt<ushort><<<dim3(32, 24), 256, 0, stream>>>(xb, Wqkvt, QKV, M_, NQKV, 2048);

  // 3. RoPE in place (Q pre-scaled to exp2 domain), V transpose
  const float qscale = 0.08838834764831845f * 1.4426950408889634f;
  rope_apply_k<<<(M_ * 1024) / 256, 256, 0, stream>>>(QKV, tab, M_ * 1024, 10, NQKV, qscale);
  rope_apply_k<<<(M_ * 256) / 256, 256, 0, stream>>>(QKV + 2048, tab, M_ * 256, 8, NQKV, 1.0f);
  transpose_v<<<dim3(4, 64, 8), dim3(32, 8), 0, stream>>>(QKV + 2560, Vt, NQKV);

  // 4. attention
  flash_attn<<<dim3(S_ / 256, B_ * H_), 256, 0, stream>>>(QKV, QKV + 2048, Vt, attn);

  // 5. output projection (f32 out)
  gemm_bt<float><<<dim3(32, 16), 256, 0, stream>>>(attn, Wot, out, M_, 2048, 2048);
}

// Round 8
// 271.437 us; speedup vs baseline: 1.0102x; 1.0102x over previous
//
#include <hip/hip_runtime.h>

// ---------------------------------------------------------------------------
// RoPE GQA attention block, MI355X bf16-MFMA implementation (round 8).
// B=2 S=2048 D=2048 H=16 HKV=4 DH=128.  head h uses kv head h%4 (torch tile).
// Round 8: flash restored to round-6 form (32 q/wave = max occupancy).
// NEW gemm256: 256-wide tiles, BK=32, TRI-buffered LDS, counted vmcnt (T4,
// never 0 in steady state), 2 phases/tile with raw s_barrier + lgkmcnt(0),
// T2 swizzle both-sides, setprio (T5). QKV: 256x192 (grid 16x16 = 1/CU),
// O: 256x128 (grid 16x16).
// ---------------------------------------------------------------------------

typedef __attribute__((ext_vector_type(8))) short  short8;
typedef __attribute__((ext_vector_type(8))) __bf16 bf16x8;
typedef __attribute__((ext_vector_type(4))) float  f32x4;

#define B_   2
#define S_   2048
#define D_   2048
#define H_   16
#define HKV_ 4
#define DH_  128
#define M_   4096  // B*S
#define NQKV 3072  // fused projection width: 2048 Q + 512 K + 512 V

static __device__ __forceinline__ ushort f2bf(float f) {
  __bf16 h = (__bf16)f;                      // native cvt (RNE)
  return __builtin_bit_cast(unsigned short, h);
}
static __device__ __forceinline__ float bf2f(ushort u) {
  union { unsigned u; float f; } v; v.u = ((unsigned)u) << 16;
  return v.f;
}
static __device__ __forceinline__ f32x4 mfma16(short8 a, short8 b, f32x4 c) {
  return __builtin_amdgcn_mfma_f32_16x16x32_bf16(
      __builtin_bit_cast(bf16x8, a), __builtin_bit_cast(bf16x8, b), c, 0, 0, 0);
}
// async global->LDS, 16B per lane; lds base must be wave-uniform.
static __device__ __forceinline__ void gload16(const ushort* g, ushort* l) {
  __builtin_amdgcn_global_load_lds(
      (const __attribute__((address_space(1))) unsigned int*)g,
      (__attribute__((address_space(3))) unsigned int*)l, 16, 0, 0);
}
template <int N>
static __device__ __forceinline__ void vmwait() {
  asm volatile("s_waitcnt vmcnt(%0)" :: "n"(N) : "memory");
}

// ---------------- elementwise f32 -> bf16 ----------------------------------
__global__ void conv_f32_bf16(const float* __restrict__ in,
                              ushort* __restrict__ out, int n4) {
  int i = blockIdx.x * blockDim.x + threadIdx.x;
  if (i >= n4) return;
  float4 v = ((const float4*)in)[i];
  ushort4 o;
  o.x = f2bf(v.x); o.y = f2bf(v.y); o.z = f2bf(v.z); o.w = f2bf(v.w);
  ((ushort4*)out)[i] = o;
}

// ---------------- transpose + convert: W[R][C] f32 -> Wt[C][R] bf16 --------
__global__ void transpose_conv(const float* __restrict__ in,
                               ushort* __restrict__ out, int R, int C) {
  __shared__ float tile[32][33];
  int c0 = blockIdx.x * 32, r0 = blockIdx.y * 32;
  int tx = threadIdx.x, ty = threadIdx.y;  // (32,8)
#pragma unroll
  for (int i = 0; i < 32; i += 8)
    tile[ty + i][tx] = in[(size_t)(r0 + ty + i) * C + c0 + tx];
  __syncthreads();
#pragma unroll
  for (int i = 0; i < 32; i += 8)
    out[(size_t)(c0 + ty + i) * R + r0 + tx] = f2bf(tile[tx][ty + i]);
}

// ---------------- bf16 transpose for V: QKV[.,2560+kv*128+d] -> [B,kv,128,S]
__global__ void transpose_v(const ushort* __restrict__ in,
                            ushort* __restrict__ out, int src_stride) {
  __shared__ ushort tile[32][33];
  int bkv = blockIdx.z;                       // b*4+kv
  const ushort* src = in + (size_t)(bkv >> 2) * S_ * src_stride + (bkv & 3) * DH_;
  ushort* dst = out + (size_t)bkv * DH_ * S_;
  int d0 = blockIdx.x * 32, s0 = blockIdx.y * 32;
  int tx = threadIdx.x, ty = threadIdx.y;
#pragma unroll
  for (int i = 0; i < 32; i += 8)
    tile[ty + i][tx] = src[(size_t)(s0 + ty + i) * src_stride + d0 + tx];
  __syncthreads();
#pragma unroll
  for (int i = 0; i < 32; i += 8)
    dst[(size_t)(d0 + ty + i) * S_ + s0 + tx] = tile[tx][ty + i];
}

// ---------------- RoPE cos/sin table [S][64] -------------------------------
__global__ void rope_table_k(float2* __restrict__ tab) {
  int i = blockIdx.x * blockDim.x + threadIdx.x;  // < S_*64
  int pos = i >> 6, f = i & 63;
  float freq = powf(10000.0f, -(float)f / 64.0f);
  float a = (float)pos * freq;
  tab[i] = make_float2(cosf(a), sinf(a));
}

// ---------------- RoPE in-place on bf16, strided rows ----------------------
__global__ void rope_apply_k(ushort* __restrict__ t,
                             const float2* __restrict__ tab,
                             int total, int ppr_shift, int row_stride,
                             float oscale) {
  int idx = blockIdx.x * blockDim.x + threadIdx.x;
  if (idx >= total) return;
  int row = idx >> ppr_shift;
  int p   = idx & ((1 << ppr_shift) - 1);
  int head = p >> 6, fi = p & 63;
  int pos = row & (S_ - 1);
  float2 cs = tab[(pos << 6) + fi];
  size_t off = (size_t)row * row_stride + head * DH_ + 2 * fi;
  ushort2 v = *(ushort2*)&t[off];
  float x0 = bf2f(v.x), x1 = bf2f(v.y);
  ushort2 o;
  o.x = f2bf((x0 * cs.x - x1 * cs.y) * oscale);
  o.y = f2bf((x0 * cs.y + x1 * cs.x) * oscale);
  *(ushort2*)&t[off] = o;
}

// ---------------- gemm256: C[M,N] = A[M,K] * Bt[N,K]^T ---------------------
// BM=256, BN=192/128, BK=32. 8 waves (2M x 4N), per-wave 128 x BN/4.
// Tri-buffered LDS; stage(t+2) issued at top of tile t (its buffer was freed
// at the end of tile t-1, two barriers ago). Counted vmcnt at end of tile t
// retires exactly tile t+1's loads (never drains to 0 in steady state).
// T2 swizzle: col ^= (row&3)<<3 on both staging source and ds_read.
template <int BN, int NF, typename OutT>
__global__ __launch_bounds__(512, 2) void gemm256(const ushort* __restrict__ A,
                                                  const ushort* __restrict__ Bt,
                                                  OutT* __restrict__ C,
                                                  int M, int N, int K) {
  __shared__ ushort As[3][256 * 32];
  __shared__ ushort Bs[3][BN * 32];
  const int tid = threadIdx.x;
  const int lane = tid & 63, w = tid >> 6;
  const int l16 = lane & 15, l4 = lane >> 4;
  const int wm = (w >> 2) * 128, wn = (w & 3) * (BN / 4);
  const int bm = blockIdx.x * 256, bn = blockIdx.y * BN;

  const ushort* gA = A  + (size_t)bm * K;
  const ushort* gB = Bt + (size_t)bn * K;
  const int srow = tid >> 2;           // 0..127
  const int scol = (tid & 3) * 8;      // 0,8,16,24

  // per-wave loads per staged tile: A=2; B: BN=128 -> 1 all waves;
  // BN=192 -> waves 0-3: 2, waves 4-7: 1.
  constexpr int CT_HI = 2 + ((BN > 128) ? 2 : 1);  // waves 0-3
  constexpr int CT_LO = 3;                          // waves 4-7 (and BN=128)

  auto stage = [&](int t, int s) {
#pragma unroll
    for (int j = 0; j < 2; ++j) {                   // A: 256 rows
      int row = j * 128 + srow;
      gload16(gA + (size_t)row * K + t * 32 + (scol ^ ((row & 3) << 3)),
              &As[s][(j * 128 + w * 16) * 32]);
    }
    {                                               // B: rows 0..127
      int row = srow;
      gload16(gB + (size_t)row * K + t * 32 + (scol ^ ((row & 3) << 3)),
              &Bs[s][(w * 16) * 32]);
    }
    if constexpr (BN > 128) {                       // B: rows 128..191
      if (tid < 256) {
        int row = 128 + srow;
        gload16(gB + (size_t)row * K + t * 32 + (scol ^ ((row & 3) << 3)),
                &Bs[s][(128 + w * 16) * 32]);
      }
    }
  };

  f32x4 acc[8][NF] = {};
  const int NT = K / 32;

  stage(0, 0);
  stage(1, 1);
  if (BN > 128 && w < 4) vmwait<CT_HI>(); else vmwait<CT_LO>();  // tile0 done
  __builtin_amdgcn_s_barrier();
  __builtin_amdgcn_sched_barrier(0);

  for (int t = 0; t < NT; ++t) {
    const int s = t - (t / 3) * 3;                  // t % 3
    if (t + 2 < NT) {
      int s2 = (t + 2) - ((t + 2) / 3) * 3;
      stage(t + 2, s2);                             // buffer freed at end t-1
    }
    short8 bfr[NF];
#pragma unroll
    for (int ph = 0; ph < 2; ++ph) {                // mh = ph
      short8 afr[4];
#pragma unroll
      for (int mf = 0; mf < 4; ++mf) {
        int row = wm + ph * 64 + mf * 16 + l16;
        int col = l4 * 8;
        afr[mf] = *(const short8*)&As[s][row * 32 + (col ^ ((row & 3) << 3))];
      }
      if (ph == 0) {
#pragma unroll
        for (int nf = 0; nf < NF; ++nf) {
          int row = wn + nf * 16 + l16;
          int col = l4 * 8;
          bfr[nf] = *(const short8*)&Bs[s][row * 32 + (col ^ ((row & 3) << 3))];
        }
      }
      __builtin_amdgcn_s_barrier();
      asm volatile("s_waitcnt lgkmcnt(0)" ::: "memory");
      __builtin_amdgcn_sched_barrier(0);
      __builtin_amdgcn_s_setprio(1);
#pragma unroll
      for (int mf = 0; mf < 4; ++mf)
#pragma unroll
        for (int nf = 0; nf < NF; ++nf)
          acc[ph * 4 + mf][nf] = mfma16(afr[mf], bfr[nf], acc[ph * 4 + mf][nf]);
      __builtin_amdgcn_s_setprio(0);
      if (ph == 1) {
        if (t + 2 < NT) {                           // steady: retire t+1 only
          if (BN > 128 && w < 4) vmwait<CT_HI>(); else vmwait<CT_LO>();
        } else if (t + 1 < NT) {
          vmwait<0>();                              // tail: drain t+1
        }
      }
      __builtin_amdgcn_s_barrier();
      __builtin_amdgcn_sched_barrier(0);
    }
  }

  // epilogue: C/D layout col=lane&15, row=(lane>>4)*4+reg
#pragma unroll
  for (int mi = 0; mi < 8; ++mi) {
#pragma unroll
    for (int nf = 0; nf < NF; ++nf) {
#pragma unroll
      for (int r = 0; r < 4; ++r) {
        size_t row = bm + wm + (mi >> 2) * 64 + (mi & 3) * 16 + l4 * 4 + r;
        size_t col = bn + wn + nf * 16 + l16;
        if constexpr (sizeof(OutT) == 2)
          C[row * N + col] = f2bf(acc[mi][nf][r]);
        else
          C[row * N + col] = acc[mi][nf][r];
      }
    }
  }
}

// ---------------- flash attention (round 6 form, restored) -----------------
// grid (S/128, B*H); 4 waves/block, wave owns 32 q rows (2 q-groups of 16);
// KBLK=64, double-buffered LDS, stage(t+1) before compute(t), single
// __syncthreads per tile. Swapped QK^T with interleaved key mapping keeps P
// entirely in registers.
__global__ __launch_bounds__(256, 2) void flash_attn(const ushort* __restrict__ Qp,
                                                     const ushort* __restrict__ Kp,
                                                     const ushort* __restrict__ Vt,
                                                     ushort* __restrict__ Oa) {
  __shared__ ushort Ks[2][64 * 128];    // [key][d], swizzle (r&3)|((r>>3)&1)<<2
  __shared__ ushort Vs[2][128 * 64];    // [d][key], swizzle d&7
  const int tid = threadIdx.x;
  const int lane = tid & 63, wave = tid >> 6;
  const int l16 = lane & 15, l4 = lane >> 4;
  const int bh = blockIdx.y;
  const int b = bh >> 4, h = bh & 15, kv = h & 3;
  const int q0 = blockIdx.x * 128 + wave * 32;

  short8 qf[2][4];
#pragma unroll
  for (int qg = 0; qg < 2; ++qg) {
    const ushort* qrow =
        Qp + ((size_t)(b * S_ + q0 + qg * 16 + l16)) * NQKV + h * DH_ + l4 * 8;
#pragma unroll
    for (int kk = 0; kk < 4; ++kk) qf[qg][kk] = *(const short8*)(qrow + kk * 32);
  }

  const ushort* kbase = Kp + (size_t)(b * S_) * NQKV + kv * DH_;
  const ushort* vbase = Vt + (size_t)(b * HKV_ + kv) * DH_ * S_;

  float mreg[2] = {-1e30f, -1e30f}, lsum[2] = {0.f, 0.f};
  f32x4 o[2][8] = {};

  const int kswz = (l16 & 3) | (((l16 >> 2) & 1) << 2);
  const int vswz = l16 & 7;

  const int krT = wave * 16 + (lane >> 4);
  const int kcT = lane & 15;
  const int vrT = wave * 32 + (lane >> 3);
  const int vcT = lane & 7;

  auto stage = [&](int t, int buf) {
#pragma unroll
    for (int i = 0; i < 4; ++i) {
      int r = krT + i * 4;
      int swz = (r & 3) | (((r >> 3) & 1) << 2);
      gload16(kbase + (size_t)(t * 64 + r) * NQKV + ((kcT ^ swz) * 8),
              &Ks[buf][(wave * 16 + i * 4) * 128]);
      int d = vrT + i * 8;
      gload16(vbase + (size_t)d * S_ + t * 64 + ((vcT ^ (d & 7)) * 8),
              &Vs[buf][(wave * 32 + i * 8) * 64]);
    }
  };

  const int NT = S_ / 64;
  stage(0, 0);
  __syncthreads();

  for (int t = 0; t < NT; ++t) {
    const int cur = t & 1;
    if (t + 1 < NT) stage(t + 1, cur ^ 1);

    f32x4 s[2][4] = {};
    __builtin_amdgcn_s_setprio(1);
#pragma unroll
    for (int c = 0; c < 4; ++c) {
      const int krow = 32 * (c >> 1) + 8 * (l16 >> 2) + 4 * (c & 1) + (l16 & 3);
#pragma unroll
      for (int kk = 0; kk < 4; ++kk) {
        short8 kf = *(const short8*)&Ks[cur][krow * 128 + (((kk * 4 + l4) ^ kswz) * 8)];
        s[0][c] = mfma16(kf, qf[0][kk], s[0][c]);
        s[1][c] = mfma16(kf, qf[1][kk], s[1][c]);
      }
    }
    __builtin_amdgcn_s_setprio(0);

    float tmax[2];
#pragma unroll
    for (int qg = 0; qg < 2; ++qg) {
      float a = fmaxf(fmaxf(s[qg][0][0], s[qg][0][1]), fmaxf(s[qg][0][2], s[qg][0][3]));
#pragma unroll
      for (int c = 1; c < 4; ++c) {
        a = fmaxf(a, fmaxf(fmaxf(s[qg][c][0], s[qg][c][1]),
                           fmaxf(s[qg][c][2], s[qg][c][3])));
      }
      a = fmaxf(a, __shfl_xor(a, 16));
      tmax[qg] = fmaxf(a, __shfl_xor(a, 32));
    }

    bool ok = (tmax[0] - mreg[0] <= 8.0f) && (tmax[1] - mreg[1] <= 8.0f);
    if (!__all(ok)) {
#pragma unroll
      for (int qg = 0; qg < 2; ++qg) {
        float mn = fmaxf(mreg[qg], tmax[qg]);
        float alpha = __builtin_amdgcn_exp2f(mreg[qg] - mn);
        mreg[qg] = mn;
        lsum[qg] *= alpha;
        float af[4];
#pragma unroll
        for (int r = 0; r < 4; ++r)
          af[r] = __shfl(alpha, (lane & 48) + l4 * 4 + r);
#pragma unroll
        for (int g = 0; g < 8; ++g)
#pragma unroll
          for (int r = 0; r < 4; ++r) o[qg][g][r] *= af[r];
      }
    }

    short8 pa[2][2];
    float rs[2] = {0.f, 0.f};
#pragma unroll
    for (int qg = 0; qg < 2; ++qg) {
#pragma unroll
      for (int ks = 0; ks < 2; ++ks) {
        short8 pk;
#pragma unroll
        for (int j = 0; j < 8; ++j) {
          float p = __builtin_amdgcn_exp2f(s[qg][2 * ks + (j >> 2)][j & 3] - mreg[qg]);
          rs[qg] += p;
          pk[j] = (short)f2bf(p);
        }
        pa[qg][ks] = pk;
      }
      float r2 = rs[qg] + __shfl_xor(rs[qg], 16);
      lsum[qg] += r2 + __shfl_xor(r2, 32);
    }

    __builtin_amdgcn_s_setprio(1);
#pragma unroll
    for (int ks = 0; ks < 2; ++ks) {
#pragma unroll
      for (int g = 0; g < 8; ++g) {
        const int d = g * 16 + l16;
        short8 vf = *(const short8*)&Vs[cur][d * 64 + (((ks * 4 + l4) ^ vswz) * 8)];
        o[0][g] = mfma16(pa[0][ks], vf, o[0][g]);
        o[1][g] = mfma16(pa[1][ks], vf, o[1][g]);
      }
    }
    __builtin_amdgcn_s_setprio(0);

    __syncthreads();
  }

#pragma unroll
  for (int qg = 0; qg < 2; ++qg) {
    float inv = 1.0f / lsum[qg];
    float invq[4];
#pragma unroll
    for (int r = 0; r < 4; ++r)
      invq[r] = __shfl(inv, (lane & 48) + l4 * 4 + r);
    ushort* op = Oa + (size_t)(b * S_ + q0 + qg * 16) * D_ + h * DH_;
#pragma unroll
    for (int g = 0; g < 8; ++g)
#pragma unroll
      for (int r = 0; r < 4; ++r)
        op[(size_t)(l4 * 4 + r) * D_ + g * 16 + l16] = f2bf(o[qg][g][r] * invq[r]);
  }
}

// ---------------------------------------------------------------------------
extern "C" void kernel_launch(void* const* d_in, const int* in_sizes, int n_in,
                              void* d_out, int out_size, void* d_ws, size_t ws_size,
                              hipStream_t stream) {
  (void)in_sizes; (void)n_in; (void)out_size; (void)ws_size;
  const float* x  = (const float*)d_in[0];
  const float* Wq = (const float*)d_in[1];
  const float* Wk = (const float*)d_in[2];
  const float* Wv = (const float*)d_in[3];
  const float* Wo = (const float*)d_in[4];
  float* out = (float*)d_out;

  size_t off = 0;
  auto carve = [&](size_t bytes) -> void* {
    void* p = (char*)d_ws + off;
    off += (bytes + 255) & ~(size_t)255;
    return p;
  };
  ushort* xb    = (ushort*)carve((size_t)M_ * D_ * 2);
  ushort* Wqkvt = (ushort*)carve((size_t)NQKV * D_ * 2);   // [3072][2048]
  ushort* Wot   = (ushort*)carve((size_t)D_ * D_ * 2);
  ushort* QKV   = (ushort*)carve((size_t)M_ * NQKV * 2);   // [4096][3072]
  ushort* Vt    = (ushort*)carve((size_t)M_ * 512 * 2);
  ushort* attn  = (ushort*)carve((size_t)M_ * D_ * 2);
  float2* tab   = (float2*)carve((size_t)S_ * 64 * sizeof(float2));

  // 1. casts / transposes of inputs (K,V weight rows appended after Q's)
  conv_f32_bf16<<<(M_ * D_ / 4 + 255) / 256, 256, 0, stream>>>(x, xb, M_ * D_ / 4);
  transpose_conv<<<dim3(64, 64), dim3(32, 8), 0, stream>>>(Wq, Wqkvt, 2048, 2048);
  transpose_conv<<<dim3(16, 64), dim3(32, 8), 0, stream>>>(Wk, Wqkvt + (size_t)2048 * 2048, 2048, 512);
  transpose_conv<<<dim3(16, 64), dim3(32, 8), 0, stream>>>(Wv, Wqkvt + (size_t)2560 * 2048, 2048, 512);
  transpose_conv<<<dim3(64, 64), dim3(32, 8), 0, stream>>>(Wo, Wot, 2048, 2048);
  rope_table_k<<<(S_ * 64) / 256, 256, 0, stream>>>(tab);

  // 2. fused QKV projection: [4096,2048] x [3072,2048]^T -> [4096,3072]
  gemm256<192, 3, ushort><<<dim3(16, 16), 512, 0, stream>>>(xb, Wqkvt, QKV, M_, NQKV, 2048);

  // 3. RoPE in place (Q pre-scaled to exp2 domain), V transpose
  const float qscale = 0.08838834764831845f * 1.4426950408889634f;
  rope_apply_k<<<(M_ * 1024) / 256, 256, 0, stream>>>(QKV, tab, M_ * 1024, 10, NQKV, qscale);
  rope_apply_k<<<(M_ * 256) / 256, 256, 0, stream>>>(QKV + 2048, tab, M_ * 256, 8, NQKV, 1.0f);
  transpose_v<<<dim3(4, 64, 8), dim3(32, 8), 0, stream>>>(QKV + 2560, Vt, NQKV);

  // 4. attention
  flash_attn<<<dim3(S_ / 128, B_ * H_), 256, 0, stream>>>(QKV, QKV + 2048, Vt, attn);

  // 5. output projection (f32 out)
  gemm256<128, 2, float><<<dim3(16, 16), 512, 0, stream>>>(attn, Wot, out, M_, 2048, 2048);
}

// Round 9
// 219.522 us; speedup vs baseline: 1.2491x; 1.2365x over previous
//
#include <hip/hip_runtime.h>

// ---------------------------------------------------------------------------
// RoPE GQA attention block, MI355X bf16-MFMA implementation (round 9).
// B=2 S=2048 D=2048 H=16 HKV=4 DH=128.  head h uses kv head h%4 (torch tile).
// Round 9: gemm8p — true 8-phase schedule (m201 template): BM=256, BK=64,
// 2 K-tiles/iter, dbuf LDS, per-phase {ds_read || gload-round || barrier ||
// lgkm(0) || 8-12 MFMA}, counted vmcnt at phases 1/3/5/7 (never 0),
// both-sides swizzle, setprio, launch_bounds(512,1) for full VGPR budget.
// Flash attention kept at round-6 form (proven 90us).
// ---------------------------------------------------------------------------

typedef __attribute__((ext_vector_type(8))) short  short8;
typedef __attribute__((ext_vector_type(8))) __bf16 bf16x8;
typedef __attribute__((ext_vector_type(4))) float  f32x4;

#define B_   2
#define S_   2048
#define D_   2048
#define H_   16
#define HKV_ 4
#define DH_  128
#define M_   4096  // B*S
#define NQKV 3072  // fused projection width: 2048 Q + 512 K + 512 V

static __device__ __forceinline__ ushort f2bf(float f) {
  __bf16 h = (__bf16)f;                      // native cvt (RNE)
  return __builtin_bit_cast(unsigned short, h);
}
static __device__ __forceinline__ float bf2f(ushort u) {
  union { unsigned u; float f; } v; v.u = ((unsigned)u) << 16;
  return v.f;
}
static __device__ __forceinline__ f32x4 mfma16(short8 a, short8 b, f32x4 c) {
  return __builtin_amdgcn_mfma_f32_16x16x32_bf16(
      __builtin_bit_cast(bf16x8, a), __builtin_bit_cast(bf16x8, b), c, 0, 0, 0);
}
// async global->LDS, 16B per lane; lds base must be wave-uniform.
static __device__ __forceinline__ void gload16(const ushort* g, ushort* l) {
  __builtin_amdgcn_global_load_lds(
      (const __attribute__((address_space(1))) unsigned int*)g,
      (__attribute__((address_space(3))) unsigned int*)l, 16, 0, 0);
}
template <int N>
static __device__ __forceinline__ void vmwait() {
  asm volatile("s_waitcnt vmcnt(%0)" :: "n"(N) : "memory");
}

// ---------------- elementwise f32 -> bf16 ----------------------------------
__global__ void conv_f32_bf16(const float* __restrict__ in,
                              ushort* __restrict__ out, int n4) {
  int i = blockIdx.x * blockDim.x + threadIdx.x;
  if (i >= n4) return;
  float4 v = ((const float4*)in)[i];
  ushort4 o;
  o.x = f2bf(v.x); o.y = f2bf(v.y); o.z = f2bf(v.z); o.w = f2bf(v.w);
  ((ushort4*)out)[i] = o;
}

// ---------------- transpose + convert: W[R][C] f32 -> Wt[C][R] bf16 --------
__global__ void transpose_conv(const float* __restrict__ in,
                               ushort* __restrict__ out, int R, int C) {
  __shared__ float tile[32][33];
  int c0 = blockIdx.x * 32, r0 = blockIdx.y * 32;
  int tx = threadIdx.x, ty = threadIdx.y;  // (32,8)
#pragma unroll
  for (int i = 0; i < 32; i += 8)
    tile[ty + i][tx] = in[(size_t)(r0 + ty + i) * C + c0 + tx];
  __syncthreads();
#pragma unroll
  for (int i = 0; i < 32; i += 8)
    out[(size_t)(c0 + ty + i) * R + r0 + tx] = f2bf(tile[tx][ty + i]);
}

// ---------------- bf16 transpose for V: QKV[.,2560+kv*128+d] -> [B,kv,128,S]
__global__ void transpose_v(const ushort* __restrict__ in,
                            ushort* __restrict__ out, int src_stride) {
  __shared__ ushort tile[32][33];
  int bkv = blockIdx.z;                       // b*4+kv
  const ushort* src = in + (size_t)(bkv >> 2) * S_ * src_stride + (bkv & 3) * DH_;
  ushort* dst = out + (size_t)bkv * DH_ * S_;
  int d0 = blockIdx.x * 32, s0 = blockIdx.y * 32;
  int tx = threadIdx.x, ty = threadIdx.y;
#pragma unroll
  for (int i = 0; i < 32; i += 8)
    tile[ty + i][tx] = src[(size_t)(s0 + ty + i) * src_stride + d0 + tx];
  __syncthreads();
#pragma unroll
  for (int i = 0; i < 32; i += 8)
    dst[(size_t)(d0 + ty + i) * S_ + s0 + tx] = tile[tx][ty + i];
}

// ---------------- RoPE cos/sin table [S][64] -------------------------------
__global__ void rope_table_k(float2* __restrict__ tab) {
  int i = blockIdx.x * blockDim.x + threadIdx.x;  // < S_*64
  int pos = i >> 6, f = i & 63;
  float freq = powf(10000.0f, -(float)f / 64.0f);
  float a = (float)pos * freq;
  tab[i] = make_float2(cosf(a), sinf(a));
}

// ---------------- RoPE in-place on bf16, strided rows ----------------------
__global__ void rope_apply_k(ushort* __restrict__ t,
                             const float2* __restrict__ tab,
                             int total, int ppr_shift, int row_stride,
                             float oscale) {
  int idx = blockIdx.x * blockDim.x + threadIdx.x;
  if (idx >= total) return;
  int row = idx >> ppr_shift;
  int p   = idx & ((1 << ppr_shift) - 1);
  int head = p >> 6, fi = p & 63;
  int pos = row & (S_ - 1);
  float2 cs = tab[(pos << 6) + fi];
  size_t off = (size_t)row * row_stride + head * DH_ + 2 * fi;
  ushort2 v = *(ushort2*)&t[off];
  float x0 = bf2f(v.x), x1 = bf2f(v.y);
  ushort2 o;
  o.x = f2bf((x0 * cs.x - x1 * cs.y) * oscale);
  o.y = f2bf((x0 * cs.y + x1 * cs.x) * oscale);
  *(ushort2*)&t[off] = o;
}

// ---------------- gemm8p: C[M,N] = A[M,K] * Bt[N,K]^T, 8-phase schedule ----
// BM=256, BN=192/128, BK=64. 8 waves (2M x 4N); per-wave 128 x BN/4.
// Iteration = 2 K-tiles (buf0, buf1), 4 quadrant-phases each.
// Phase: {afr ds_read (+bfr at quad0) | 1-2 gload rounds | barrier |
//         lgkm(0) | setprio 2*2*NF MFMA | counted vmcnt | barrier}.
// gload round = 64 rows x 64 cols (1 load/thread). A rounds 0..3, B rounds
// 0..NF-1. Fill slots (steady): ph0:A1,A3(tb) ph1:B0,B1(ta2) ph2:[B2],A0(ta2)
// ph3:A2(ta2) ph4:A1,A3(ta2) ph5:B0,B1(tb2) ph6:[B2],A0(tb2) ph7:A2(tb2).
// vmcnt levels derived from the FIFO ledger; never 0 in the loop.
template <int BN, int NF, typename OutT>
__global__ __launch_bounds__(512, 1) void gemm8p(const ushort* __restrict__ A,
                                                 const ushort* __restrict__ Bt,
                                                 OutT* __restrict__ C,
                                                 int M, int N, int K) {
  __shared__ ushort As[2][256 * 64];
  __shared__ ushort Bs[2][BN * 64];
  const int tid = threadIdx.x;
  const int lane = tid & 63, w = tid >> 6;
  const int l16 = lane & 15, l4 = lane >> 4;
  const int wm = (w >> 2) * 128, wn = (w & 3) * (BN / 4);
  const int bm = blockIdx.x * 256, bn = blockIdx.y * BN;
  const int swz = l16 & 7;                 // ds_read colblk swizzle

  const ushort* gA = A  + (size_t)bm * K;
  const ushort* gB = Bt + (size_t)bn * K;
  const int srow = tid >> 3;               // 0..63 within a round
  const int scb  = tid & 7;                // colblk 0..7
  const int sswz = srow & 7;

  auto stageA = [&](int t, int s, int g) {
    int row = g * 64 + srow;
    gload16(gA + (size_t)row * K + t * 64 + ((scb ^ sswz) * 8),
            &As[s][(g * 64 + w * 8) * 64]);
  };
  auto stageB = [&](int t, int s, int g) {
    int row = g * 64 + srow;
    gload16(gB + (size_t)row * K + t * 64 + ((scb ^ sswz) * 8),
            &Bs[s][(g * 64 + w * 8) * 64]);
  };
  auto stageB2 = [&](int t, int s) {       // third B round only for BN=192
    if constexpr (NF == 3) stageB(t, s, 2);
  };

  constexpr int VM_A = (NF == 3) ? 9 : 8;  // end of phases 1,5
  constexpr int VM_B = (NF == 3) ? 7 : 6;  // end of phases 3,7 (+prologue)

  f32x4 acc[8][NF] = {};
  short8 bfr[NF][2];
  const int NT  = K / 64;
  const int NIT = K / 128;

  // ---- prologue: tile0 full, tile1 all but A1,A3 (FIFO matches steady) ----
  stageB(0, 0, 0); stageB(0, 0, 1); stageB2(0, 0);
  stageA(0, 0, 0); stageA(0, 0, 2);
  stageA(0, 0, 1); stageA(0, 0, 3);
  stageB(1, 1, 0); stageB(1, 1, 1); stageB2(1, 1);
  stageA(1, 1, 0); stageA(1, 1, 2);
  vmwait<VM_B>();
  __builtin_amdgcn_s_barrier();
  __builtin_amdgcn_sched_barrier(0);

#define GPHASE(S, J, ISSUES, VMW)                                             \
  {                                                                           \
    short8 afr[2][2];                                                         \
    _Pragma("unroll")                                                         \
    for (int mf = 0; mf < 2; ++mf) {                                          \
      _Pragma("unroll")                                                       \
      for (int kk = 0; kk < 2; ++kk) {                                        \
        int row = wm + (J) * 32 + mf * 16 + l16;                              \
        afr[mf][kk] =                                                         \
            *(const short8*)&As[S][row * 64 + (((kk * 4 + l4) ^ swz) * 8)];   \
      }                                                                       \
    }                                                                         \
    if ((J) == 0) {                                                           \
      _Pragma("unroll")                                                       \
      for (int nf = 0; nf < NF; ++nf) {                                       \
        _Pragma("unroll")                                                     \
        for (int kk = 0; kk < 2; ++kk) {                                      \
          int row = wn + nf * 16 + l16;                                       \
          bfr[nf][kk] =                                                       \
              *(const short8*)&Bs[S][row * 64 + (((kk * 4 + l4) ^ swz) * 8)]; \
        }                                                                     \
      }                                                                       \
    }                                                                         \
    ISSUES;                                                                   \
    __builtin_amdgcn_s_barrier();                                             \
    asm volatile("s_waitcnt lgkmcnt(0)" ::: "memory");                        \
    __builtin_amdgcn_sched_barrier(0);                                        \
    __builtin_amdgcn_s_setprio(1);                                            \
    _Pragma("unroll")                                                         \
    for (int kk = 0; kk < 2; ++kk) {                                          \
      _Pragma("unroll")                                                       \
      for (int mf = 0; mf < 2; ++mf) {                                        \
        _Pragma("unroll")                                                     \
        for (int nf = 0; nf < NF; ++nf)                                       \
          acc[(J) * 2 + mf][nf] =                                             \
              mfma16(afr[mf][kk], bfr[nf][kk], acc[(J) * 2 + mf][nf]);        \
      }                                                                       \
    }                                                                         \
    __builtin_amdgcn_s_setprio(0);                                            \
    VMW;                                                                      \
    __builtin_amdgcn_s_barrier();                                             \
    __builtin_amdgcn_sched_barrier(0);                                        \
  }

  for (int i = 0; i < NIT; ++i) {
    const int tb  = 2 * i + 1;
    const int ta2 = (2 * i + 2 < NT) ? 2 * i + 2 : NT - 1;   // clamped tail
    const int tb2 = (2 * i + 3 < NT) ? 2 * i + 3 : NT - 1;
    // tile a = 2i from buf0
    GPHASE(0, 0, (stageA(tb, 1, 1), stageA(tb, 1, 3)), (void)0)
    GPHASE(0, 1, (stageB(ta2, 0, 0), stageB(ta2, 0, 1)), vmwait<VM_A>())
    GPHASE(0, 2, (stageB2(ta2, 0), stageA(ta2, 0, 0)), (void)0)
    GPHASE(0, 3, (stageA(ta2, 0, 2)), vmwait<VM_B>())
    // tile b = 2i+1 from buf1
    GPHASE(1, 0, (stageA(ta2, 0, 1), stageA(ta2, 0, 3)), (void)0)
    GPHASE(1, 1, (stageB(tb2, 1, 0), stageB(tb2, 1, 1)), vmwait<VM_A>())
    GPHASE(1, 2, (stageB2(tb2, 1), stageA(tb2, 1, 0)), (void)0)
    GPHASE(1, 3, (stageA(tb2, 1, 2)), vmwait<VM_B>())
  }
#undef GPHASE

  asm volatile("s_waitcnt vmcnt(0)" ::: "memory");  // drain LDS DMA pre-exit

  // epilogue: C/D layout col=lane&15, row=(lane>>4)*4+reg
#pragma unroll
  for (int mi = 0; mi < 8; ++mi) {
#pragma unroll
    for (int nf = 0; nf < NF; ++nf) {
#pragma unroll
      for (int r = 0; r < 4; ++r) {
        size_t row = bm + wm + (mi >> 1) * 32 + (mi & 1) * 16 + l4 * 4 + r;
        size_t col = bn + wn + nf * 16 + l16;
        if constexpr (sizeof(OutT) == 2)
          C[row * N + col] = f2bf(acc[mi][nf][r]);
        else
          C[row * N + col] = acc[mi][nf][r];
      }
    }
  }
}

// ---------------- flash attention (round 6 form, proven) -------------------
// grid (S/128, B*H); 4 waves/block, wave owns 32 q rows (2 q-groups of 16);
// KBLK=64, double-buffered LDS, stage(t+1) before compute(t), single
// __syncthreads per tile. Swapped QK^T with interleaved key mapping keeps P
// entirely in registers.
__global__ __launch_bounds__(256, 2) void flash_attn(const ushort* __restrict__ Qp,
                                                     const ushort* __restrict__ Kp,
                                                     const ushort* __restrict__ Vt,
                                                     ushort* __restrict__ Oa) {
  __shared__ ushort Ks[2][64 * 128];    // [key][d], swizzle (r&3)|((r>>3)&1)<<2
  __shared__ ushort Vs[2][128 * 64];    // [d][key], swizzle d&7
  const int tid = threadIdx.x;
  const int lane = tid & 63, wave = tid >> 6;
  const int l16 = lane & 15, l4 = lane >> 4;
  const int bh = blockIdx.y;
  const int b = bh >> 4, h = bh & 15, kv = h & 3;
  const int q0 = blockIdx.x * 128 + wave * 32;

  short8 qf[2][4];
#pragma unroll
  for (int qg = 0; qg < 2; ++qg) {
    const ushort* qrow =
        Qp + ((size_t)(b * S_ + q0 + qg * 16 + l16)) * NQKV + h * DH_ + l4 * 8;
#pragma unroll
    for (int kk = 0; kk < 4; ++kk) qf[qg][kk] = *(const short8*)(qrow + kk * 32);
  }

  const ushort* kbase = Kp + (size_t)(b * S_) * NQKV + kv * DH_;
  const ushort* vbase = Vt + (size_t)(b * HKV_ + kv) * DH_ * S_;

  float mreg[2] = {-1e30f, -1e30f}, lsum[2] = {0.f, 0.f};
  f32x4 o[2][8] = {};

  const int kswz = (l16 & 3) | (((l16 >> 2) & 1) << 2);
  const int vswz = l16 & 7;

  const int krT = wave * 16 + (lane >> 4);
  const int kcT = lane & 15;
  const int vrT = wave * 32 + (lane >> 3);
  const int vcT = lane & 7;

  auto stage = [&](int t, int buf) {
#pragma unroll
    for (int i = 0; i < 4; ++i) {
      int r = krT + i * 4;
      int swzk = (r & 3) | (((r >> 3) & 1) << 2);
      gload16(kbase + (size_t)(t * 64 + r) * NQKV + ((kcT ^ swzk) * 8),
              &Ks[buf][(wave * 16 + i * 4) * 128]);
      int d = vrT + i * 8;
      gload16(vbase + (size_t)d * S_ + t * 64 + ((vcT ^ (d & 7)) * 8),
              &Vs[buf][(wave * 32 + i * 8) * 64]);
    }
  };

  const int NT = S_ / 64;
  stage(0, 0);
  __syncthreads();

  for (int t = 0; t < NT; ++t) {
    const int cur = t & 1;
    if (t + 1 < NT) stage(t + 1, cur ^ 1);

    f32x4 s[2][4] = {};
    __builtin_amdgcn_s_setprio(1);
#pragma unroll
    for (int c = 0; c < 4; ++c) {
      const int krow = 32 * (c >> 1) + 8 * (l16 >> 2) + 4 * (c & 1) + (l16 & 3);
#pragma unroll
      for (int kk = 0; kk < 4; ++kk) {
        short8 kf = *(const short8*)&Ks[cur][krow * 128 + (((kk * 4 + l4) ^ kswz) * 8)];
        s[0][c] = mfma16(kf, qf[0][kk], s[0][c]);
        s[1][c] = mfma16(kf, qf[1][kk], s[1][c]);
      }
    }
    __builtin_amdgcn_s_setprio(0);

    float tmax[2];
#pragma unroll
    for (int qg = 0; qg < 2; ++qg) {
      float a = fmaxf(fmaxf(s[qg][0][0], s[qg][0][1]), fmaxf(s[qg][0][2], s[qg][0][3]));
#pragma unroll
      for (int c = 1; c < 4; ++c) {
        a = fmaxf(a, fmaxf(fmaxf(s[qg][c][0], s[qg][c][1]),
                           fmaxf(s[qg][c][2], s[qg][c][3])));
      }
      a = fmaxf(a, __shfl_xor(a, 16));
      tmax[qg] = fmaxf(a, __shfl_xor(a, 32));
    }

    bool ok = (tmax[0] - mreg[0] <= 8.0f) && (tmax[1] - mreg[1] <= 8.0f);
    if (!__all(ok)) {
#pragma unroll
      for (int qg = 0; qg < 2; ++qg) {
        float mn = fmaxf(mreg[qg], tmax[qg]);
        float alpha = __builtin_amdgcn_exp2f(mreg[qg] - mn);
        mreg[qg] = mn;
        lsum[qg] *= alpha;
        float af[4];
#pragma unroll
        for (int r = 0; r < 4; ++r)
          af[r] = __shfl(alpha, (lane & 48) + l4 * 4 + r);
#pragma unroll
        for (int g = 0; g < 8; ++g)
#pragma unroll
          for (int r = 0; r < 4; ++r) o[qg][g][r] *= af[r];
      }
    }

    short8 pa[2][2];
    float rs[2] = {0.f, 0.f};
#pragma unroll
    for (int qg = 0; qg < 2; ++qg) {
#pragma unroll
      for (int ks = 0; ks < 2; ++ks) {
        short8 pk;
#pragma unroll
        for (int j = 0; j < 8; ++j) {
          float p = __builtin_amdgcn_exp2f(s[qg][2 * ks + (j >> 2)][j & 3] - mreg[qg]);
          rs[qg] += p;
          pk[j] = (short)f2bf(p);
        }
        pa[qg][ks] = pk;
      }
      float r2 = rs[qg] + __shfl_xor(rs[qg], 16);
      lsum[qg] += r2 + __shfl_xor(r2, 32);
    }

    __builtin_amdgcn_s_setprio(1);
#pragma unroll
    for (int ks = 0; ks < 2; ++ks) {
#pragma unroll
      for (int g = 0; g < 8; ++g) {
        const int d = g * 16 + l16;
        short8 vf = *(const short8*)&Vs[cur][d * 64 + (((ks * 4 + l4) ^ vswz) * 8)];
        o[0][g] = mfma16(pa[0][ks], vf, o[0][g]);
        o[1][g] = mfma16(pa[1][ks], vf, o[1][g]);
      }
    }
    __builtin_amdgcn_s_setprio(0);

    __syncthreads();
  }

#pragma unroll
  for (int qg = 0; qg < 2; ++qg) {
    float inv = 1.0f / lsum[qg];
    float invq[4];
#pragma unroll
    for (int r = 0; r < 4; ++r)
      invq[r] = __shfl(inv, (lane & 48) + l4 * 4 + r);
    ushort* op = Oa + (size_t)(b * S_ + q0 + qg * 16) * D_ + h * DH_;
#pragma unroll
    for (int g = 0; g < 8; ++g)
#pragma unroll
      for (int r = 0; r < 4; ++r)
        op[(size_t)(l4 * 4 + r) * D_ + g * 16 + l16] = f2bf(o[qg][g][r] * invq[r]);
  }
}

// ---------------------------------------------------------------------------
extern "C" void kernel_launch(void* const* d_in, const int* in_sizes, int n_in,
                              void* d_out, int out_size, void* d_ws, size_t ws_size,
                              hipStream_t stream) {
  (void)in_sizes; (void)n_in; (void)out_size; (void)ws_size;
  const float* x  = (const float*)d_in[0];
  const float* Wq = (const float*)d_in[1];
  const float* Wk = (const float*)d_in[2];
  const float* Wv = (const float*)d_in[3];
  const float* Wo = (const float*)d_in[4];
  float* out = (float*)d_out;

  size_t off = 0;
  auto carve = [&](size_t bytes) -> void* {
    void* p = (char*)d_ws + off;
    off += (bytes + 255) & ~(size_t)255;
    return p;
  };
  ushort* xb    = (ushort*)carve((size_t)M_ * D_ * 2);
  ushort* Wqkvt = (ushort*)carve((size_t)NQKV * D_ * 2);   // [3072][2048]
  ushort* Wot   = (ushort*)carve((size_t)D_ * D_ * 2);
  ushort* QKV   = (ushort*)carve((size_t)M_ * NQKV * 2);   // [4096][3072]
  ushort* Vt    = (ushort*)carve((size_t)M_ * 512 * 2);
  ushort* attn  = (ushort*)carve((size_t)M_ * D_ * 2);
  float2* tab   = (float2*)carve((size_t)S_ * 64 * sizeof(float2));

  // 1. casts / transposes of inputs (K,V weight rows appended after Q's)
  conv_f32_bf16<<<(M_ * D_ / 4 + 255) / 256, 256, 0, stream>>>(x, xb, M_ * D_ / 4);
  transpose_conv<<<dim3(64, 64), dim3(32, 8), 0, stream>>>(Wq, Wqkvt, 2048, 2048);
  transpose_conv<<<dim3(16, 64), dim3(32, 8), 0, stream>>>(Wk, Wqkvt + (size_t)2048 * 2048, 2048, 512);
  transpose_conv<<<dim3(16, 64), dim3(32, 8), 0, stream>>>(Wv, Wqkvt + (size_t)2560 * 2048, 2048, 512);
  transpose_conv<<<dim3(64, 64), dim3(32, 8), 0, stream>>>(Wo, Wot, 2048, 2048);
  rope_table_k<<<(S_ * 64) / 256, 256, 0, stream>>>(tab);

  // 2. fused QKV projection: [4096,2048] x [3072,2048]^T -> [4096,3072]
  gemm8p<192, 3, ushort><<<dim3(16, 16), 512, 0, stream>>>(xb, Wqkvt, QKV, M_, NQKV, 2048);

  // 3. RoPE in place (Q pre-scaled to exp2 domain), V transpose
  const float qscale = 0.08838834764831845f * 1.4426950408889634f;
  rope_apply_k<<<(M_ * 1024) / 256, 256, 0, stream>>>(QKV, tab, M_ * 1024, 10, NQKV, qscale);
  rope_apply_k<<<(M_ * 256) / 256, 256, 0, stream>>>(QKV + 2048, tab, M_ * 256, 8, NQKV, 1.0f);
  transpose_v<<<dim3(4, 64, 8), dim3(32, 8), 0, stream>>>(QKV + 2560, Vt, NQKV);

  // 4. attention
  flash_attn<<<dim3(S_ / 128, B_ * H_), 256, 0, stream>>>(QKV, QKV + 2048, Vt, attn);

  // 5. output projection (f32 out)
  gemm8p<128, 2, float><<<dim3(16, 16), 512, 0, stream>>>(attn, Wot, out, M_, 2048, 2048);
}